// Round 1
// baseline (449.871 us; speedup 1.0000x reference)
//
#include <hip/hip_runtime.h>
#include <hip/hip_bf16.h>
#include <stdint.h>

#define V 32000
#define E 256
#define H 256
#define KCTX 3
#define S 2048
#define B 4
#define M (S * B)      // 8192 rows
#define K1 (KCTX * E)  // 768

typedef __attribute__((ext_vector_type(8))) short short8;
typedef __attribute__((ext_vector_type(4))) float f32x4;

static __device__ __forceinline__ unsigned short f2bf(float f) {
  union { float f; unsigned u; } v; v.f = f;
  unsigned u = v.u;
  // round-to-nearest-even
  unsigned r = (u + 0x7fffu + ((u >> 16) & 1u)) >> 16;
  return (unsigned short)r;
}

// ---------------------------------------------------------------------------
// Transpose + cast: in (R x C) f32  ->  out (C x R) bf16
// Requires R % 32 == 0 and C % 32 == 0 (true: 768,256,32000).
// ---------------------------------------------------------------------------
__global__ void k_transpose_cast(const float* __restrict__ in,
                                 unsigned short* __restrict__ out,
                                 int R, int C) {
  __shared__ float tile[32][33];
  int bx = blockIdx.x;               // column-tile
  int by = blockIdx.y;               // row-tile
  int tx = threadIdx.x & 31;
  int ty = threadIdx.x >> 5;         // 0..7
#pragma unroll
  for (int i = 0; i < 32; i += 8)
    tile[ty + i][tx] = in[(size_t)(by * 32 + ty + i) * C + bx * 32 + tx];
  __syncthreads();
#pragma unroll
  for (int i = 0; i < 32; i += 8)
    out[(size_t)(bx * 32 + ty + i) * R + by * 32 + tx] = f2bf(tile[tx][ty + i]);
}

// ---------------------------------------------------------------------------
// Stage 1: h[m][n] = silu( x[m] @ w1 + b1 ),  m in [0,8192), n in [0,256)
// x[m][k] = embed[ tok(m, k/256) ][ k%256 ],  gathered on the fly (f32->bf16).
// One wave computes a 16(M) x 64(N) tile; 2048 waves total.
// ---------------------------------------------------------------------------
__global__ __launch_bounds__(256) void k_stage1(
    const int* __restrict__ tok, const float* __restrict__ embed,
    const unsigned short* __restrict__ w1T,  // (H x K1) bf16, w1T[n][k]
    const float* __restrict__ b1, unsigned short* __restrict__ hbuf) {
  int gid = blockIdx.x * blockDim.x + threadIdx.x;
  int wv = gid >> 6;        // 0..2047
  int l = threadIdx.x & 63;
  int mt = wv >> 2;         // 0..511
  int n0 = (wv & 3) * 64;
  int m = mt * 16 + (l & 15);
  int s = m >> 2, b = m & 3;

  int tk[KCTX];
#pragma unroll
  for (int kk = 0; kk < KCTX; kk++) {
    int t = s - KCTX + kk;
    tk[kk] = (t >= 0) ? tok[t * B + b] : 0;
  }

  f32x4 zero = {0.f, 0.f, 0.f, 0.f};
  f32x4 acc[4];
#pragma unroll
  for (int ni = 0; ni < 4; ni++) acc[ni] = zero;

  int kr = (l >> 4) * 8;  // lane's k offset within a K-32 chunk
#pragma unroll
  for (int kt = 0; kt < 24; kt++) {  // 24 * 32 = 768 = K1
    int k = kt * 32 + kr;
    int kk = k >> 8;        // constant after unroll
    int e = k & 255;
    const float* ep = embed + (size_t)tk[kk] * E + e;
    f32x4 e0 = *reinterpret_cast<const f32x4*>(ep);
    f32x4 e1 = *reinterpret_cast<const f32x4*>(ep + 4);
    short8 a;
#pragma unroll
    for (int j = 0; j < 4; j++) {
      a[j]     = (short)f2bf(e0[j]);
      a[4 + j] = (short)f2bf(e1[j]);
    }
#pragma unroll
    for (int ni = 0; ni < 4; ni++) {
      int n = n0 + ni * 16 + (l & 15);
      short8 bf = *reinterpret_cast<const short8*>(w1T + (size_t)n * K1 + k);
      acc[ni] = __builtin_amdgcn_mfma_f32_16x16x32_bf16(a, bf, acc[ni], 0, 0, 0);
    }
  }

  // epilogue: + b1, silu, cast bf16, store
  int rbase = mt * 16 + ((l >> 4) * 4);
#pragma unroll
  for (int ni = 0; ni < 4; ni++) {
    int n = n0 + ni * 16 + (l & 15);
    float bias = b1[n];
#pragma unroll
    for (int j = 0; j < 4; j++) {
      float vv = acc[ni][j] + bias;
      float sv = vv / (1.0f + __expf(-vv));
      hbuf[(size_t)(rbase + j) * H + n] = f2bf(sv);
    }
  }
}

// ---------------------------------------------------------------------------
// Stage 2: out[m][v] = h[m] @ w2 + b2   (8192 x 32000, K = 256)
// Block: 256 threads (4 waves, 2x2), tile 128M x 128N, BK = 64, 4 K-steps.
// Reg-staged LDS with XOR swizzle (chunk-of-8-bf16 granularity).
// XCD-aware block swizzle: 16000 blocks = 8 * 2000.
// ---------------------------------------------------------------------------
__global__ __launch_bounds__(256, 2) void k_stage2(
    const unsigned short* __restrict__ hbuf,  // (8192 x 256) bf16
    const unsigned short* __restrict__ w2T,   // (32000 x 256) bf16
    const float* __restrict__ b2, float* __restrict__ out) {
  __shared__ unsigned short lds[2 * 128 * 64];  // A tile then B tile, 32 KiB
  unsigned short* ldsA = lds;
  unsigned short* ldsB = lds + 128 * 64;

  int bid = blockIdx.x;
  // XCD swizzle: consecutive-per-XCD chunks, M-fastest so each XCD covers a
  // narrow N range -> its w2T slice (~2 MB) stays L2-resident.
  int rb = (bid & 7) * 2000 + (bid >> 3);
  int mtile = rb & 63;   // 64 M-tiles
  int ntile = rb >> 6;   // 250 N-tiles
  int m_base = mtile * 128, n_base = ntile * 128;

  int t = threadIdx.x;
  int l = t & 63;
  int wv = t >> 6;
  int wm = wv >> 1, wn = wv & 1;  // 2x2 wave grid, each wave 64x64

  f32x4 zero = {0.f, 0.f, 0.f, 0.f};
  f32x4 acc[4][4];
#pragma unroll
  for (int mi = 0; mi < 4; mi++)
#pragma unroll
    for (int ni = 0; ni < 4; ni++) acc[mi][ni] = zero;

  for (int kt = 0; kt < 4; kt++) {
    int gk0 = kt * 64;
    short8 regA[4], regB[4];
#pragma unroll
    for (int j = 0; j < 4; j++) {
      int slot = j * 256 + t;      // 0..1023 16B-chunks
      int row = slot >> 3;         // 0..127
      int c8 = slot & 7;           // chunk within row
      regA[j] = *reinterpret_cast<const short8*>(
          hbuf + (size_t)(m_base + row) * 256 + gk0 + c8 * 8);
      regB[j] = *reinterpret_cast<const short8*>(
          w2T + (size_t)(n_base + row) * 256 + gk0 + c8 * 8);
    }
    __syncthreads();  // previous step's compute done before overwrite
#pragma unroll
    for (int j = 0; j < 4; j++) {
      int slot = j * 256 + t;
      int row = slot >> 3;
      int c8s = (slot & 7) ^ (row & 7);  // XOR swizzle
      *reinterpret_cast<short8*>(ldsA + row * 64 + c8s * 8) = regA[j];
      *reinterpret_cast<short8*>(ldsB + row * 64 + c8s * 8) = regB[j];
    }
    __syncthreads();

#pragma unroll
    for (int ks = 0; ks < 2; ks++) {
      int c8 = ks * 4 + (l >> 4);  // lane's 16B chunk index within BK=64
      short8 af[4], bfr[4];
#pragma unroll
      for (int mi = 0; mi < 4; mi++) {
        int row = wm * 64 + mi * 16 + (l & 15);
        af[mi] = *reinterpret_cast<const short8*>(
            ldsA + row * 64 + (c8 ^ (row & 7)) * 8);
      }
#pragma unroll
      for (int ni = 0; ni < 4; ni++) {
        int row = wn * 64 + ni * 16 + (l & 15);
        bfr[ni] = *reinterpret_cast<const short8*>(
            ldsB + row * 64 + (c8 ^ (row & 7)) * 8);
      }
#pragma unroll
      for (int mi = 0; mi < 4; mi++)
#pragma unroll
        for (int ni = 0; ni < 4; ni++)
          acc[mi][ni] = __builtin_amdgcn_mfma_f32_16x16x32_bf16(
              af[mi], bfr[ni], acc[mi][ni], 0, 0, 0);
    }
  }

  // epilogue: + b2, f32 store
#pragma unroll
  for (int ni = 0; ni < 4; ni++) {
    int col = n_base + wn * 64 + ni * 16 + (l & 15);
    float bias = b2[col];
#pragma unroll
    for (int mi = 0; mi < 4; mi++) {
      int row0 = m_base + wm * 64 + mi * 16 + ((l >> 4) * 4);
#pragma unroll
      for (int j = 0; j < 4; j++)
        out[(size_t)(row0 + j) * V + col] = acc[mi][ni][j] + bias;
    }
  }
}

// ---------------------------------------------------------------------------
extern "C" void kernel_launch(void* const* d_in, const int* in_sizes, int n_in,
                              void* d_out, int out_size, void* d_ws,
                              size_t ws_size, hipStream_t stream) {
  const int* tokens = (const int*)d_in[0];     // (S, B)
  const float* embed = (const float*)d_in[1];  // (V, E)
  const float* w1 = (const float*)d_in[2];     // (K1, H)
  const float* b1 = (const float*)d_in[3];     // (H)
  const float* w2 = (const float*)d_in[4];     // (H, V)
  const float* b2 = (const float*)d_in[5];     // (V)
  float* out = (float*)d_out;

  // workspace layout (bf16 = ushort)
  unsigned short* w2T = (unsigned short*)d_ws;          // V*E   = 8,192,000
  unsigned short* w1T = w2T + (size_t)V * E;            // H*K1  =   196,608
  unsigned short* hb  = w1T + (size_t)H * K1;           // M*H   = 2,097,152
  // total 20,971,520 bytes

  // prep: w2 (H x V) -> w2T (V x H) bf16
  k_transpose_cast<<<dim3(V / 32, H / 32), 256, 0, stream>>>(w2, w2T, H, V);
  // prep: w1 (K1 x H) -> w1T (H x K1) bf16
  k_transpose_cast<<<dim3(H / 32, K1 / 32), 256, 0, stream>>>(w1, w1T, K1, H);
  // stage 1: h = silu(x @ w1 + b1), bf16
  k_stage1<<<512, 256, 0, stream>>>(tokens, embed, w1T, b1, hb);
  // stage 2: out = h @ w2 + b2
  k_stage2<<<16000, 256, 0, stream>>>(hb, w2T, b2, out);
}

// Round 3
// 434.584 us; speedup vs baseline: 1.0352x; 1.0352x over previous
//
#include <hip/hip_runtime.h>
#include <hip/hip_bf16.h>
#include <stdint.h>

#define V 32000
#define E 256
#define H 256
#define KCTX 3
#define S 2048
#define B 4
#define M (S * B)      // 8192 rows
#define K1 (KCTX * E)  // 768

typedef __attribute__((ext_vector_type(8))) short s16x8;
typedef __attribute__((ext_vector_type(4))) short s16x4;
typedef __attribute__((ext_vector_type(4))) float f32x4;

typedef const __attribute__((address_space(1))) unsigned short* gas_t;
typedef __attribute__((address_space(3))) unsigned short* las_t;

static __device__ __forceinline__ unsigned short f2bf(float f) {
  union { float f; unsigned u; } v; v.f = f;
  unsigned u = v.u;
  unsigned r = (u + 0x7fffu + ((u >> 16) & 1u)) >> 16;  // RNE
  return (unsigned short)r;
}

// ---------------------------------------------------------------------------
// Transpose + cast: in (R x C) f32  ->  out (C x R) bf16.  R%32==0, C%32==0.
// ---------------------------------------------------------------------------
__global__ void k_transpose_cast(const float* __restrict__ in,
                                 unsigned short* __restrict__ out,
                                 int R, int C) {
  __shared__ float tile[32][33];
  int bx = blockIdx.x;               // column-tile
  int by = blockIdx.y;               // row-tile
  int tx = threadIdx.x & 31;
  int ty = threadIdx.x >> 5;         // 0..7
#pragma unroll
  for (int i = 0; i < 32; i += 8)
    tile[ty + i][tx] = in[(size_t)(by * 32 + ty + i) * C + bx * 32 + tx];
  __syncthreads();
#pragma unroll
  for (int i = 0; i < 32; i += 8)
    out[(size_t)(bx * 32 + ty + i) * R + by * 32 + tx] = f2bf(tile[tx][ty + i]);
}

// ---------------------------------------------------------------------------
// Stage 1: h = silu(x @ w1 + b1), h bf16 (8192 x 256).
// Block = 4 waves = one 16-row M-tile. The 16x768 bf16 x-tile is gathered
// from embed (f32) ONCE per block into LDS (conversion amortized 4x),
// then each wave MFMAs a 64-col N-slice. w1T is L2-resident (0.4 MB).
// ---------------------------------------------------------------------------
__global__ __launch_bounds__(256) void k_stage1(
    const int* __restrict__ tok, const float* __restrict__ embed,
    const unsigned short* __restrict__ w1T,  // (H x K1) bf16, w1T[n][k]
    const float* __restrict__ b1, unsigned short* __restrict__ hbuf) {
  __shared__ unsigned short xlds[16][K1 + 8];  // +8 pad: 2-way alias (free)
  __shared__ int toks[48];
  int bid = blockIdx.x;        // 0..511
  int t = threadIdx.x;
  int m0 = bid * 16;

  if (t < 48) {
    int r = t / 3, kk = t - r * 3;
    int m = m0 + r, s = m >> 2, bb = m & 3;
    int tp = s - KCTX + kk;
    toks[t] = (tp >= 0) ? tok[tp * B + bb] : 0;
  }
  __syncthreads();

  // gather + cast: 16 rows x 3 tokens x 256 f32 = 3072 float4 chunks
#pragma unroll
  for (int j = 0; j < 12; j++) {
    int c = j * 256 + t;
    int r = c / 192;           // 192 float4 per x-row
    int cc = c - r * 192;      // 0..191
    int kk = cc >> 6;
    int e4 = cc & 63;
    f32x4 v = *reinterpret_cast<const f32x4*>(
        embed + (size_t)toks[r * 3 + kk] * E + e4 * 4);
    s16x4 o;
#pragma unroll
    for (int jj = 0; jj < 4; jj++) o[jj] = (short)f2bf(v[jj]);
    *reinterpret_cast<s16x4*>(&xlds[r][cc * 4]) = o;
  }
  __syncthreads();

  int l = t & 63;
  int wv = t >> 6;
  int n0 = wv * 64;

  f32x4 zero = {0.f, 0.f, 0.f, 0.f};
  f32x4 acc[4];
#pragma unroll
  for (int ni = 0; ni < 4; ni++) acc[ni] = zero;

#pragma unroll
  for (int kt = 0; kt < 24; kt++) {
    s16x8 a = *reinterpret_cast<const s16x8*>(&xlds[l & 15][kt * 32 + (l >> 4) * 8]);
#pragma unroll
    for (int ni = 0; ni < 4; ni++) {
      int n = n0 + ni * 16 + (l & 15);
      s16x8 bf = *reinterpret_cast<const s16x8*>(
          w1T + (size_t)n * K1 + kt * 32 + (l >> 4) * 8);
      acc[ni] = __builtin_amdgcn_mfma_f32_16x16x32_bf16(a, bf, acc[ni], 0, 0, 0);
    }
  }

  int rbase = m0 + (l >> 4) * 4;
#pragma unroll
  for (int ni = 0; ni < 4; ni++) {
    int n = n0 + ni * 16 + (l & 15);
    float bias = b1[n];
#pragma unroll
    for (int j = 0; j < 4; j++) {
      float vv = acc[ni][j] + bias;
      float sv = vv / (1.0f + __expf(-vv));
      hbuf[(size_t)(rbase + j) * H + n] = f2bf(sv);
    }
  }
}

// ---------------------------------------------------------------------------
// Stage 2: out = h @ w2 + b2  (8192 x 32000, K=256).
// m97 structure: 128x128 tile, BK=64, 4 waves (2x2), global_load_lds width=16
// into LINEAR LDS (rule 21: no swizzle on either side), 2 barriers/K-step.
// XCD-aware block swizzle (16000 = 8 x 2000, M-fastest -> per-XCD w2T slice
// ~2MB stays L2-resident).
// ---------------------------------------------------------------------------
__global__ __launch_bounds__(256, 2) void k_stage2(
    const unsigned short* __restrict__ hbuf,  // (8192 x 256) bf16
    const unsigned short* __restrict__ w2T,   // (32000 x 256) bf16
    const float* __restrict__ b2, float* __restrict__ out) {
  __shared__ unsigned short lds[2 * 128 * 64];  // A tile, B tile: 32 KiB
  unsigned short* ldsA = lds;
  unsigned short* ldsB = lds + 128 * 64;

  int bid = blockIdx.x;
  int rb = (bid & 7) * 2000 + (bid >> 3);
  int mtile = rb & 63;   // 64 M-tiles
  int ntile = rb >> 6;   // 250 N-tiles
  int m_base = mtile * 128, n_base = ntile * 128;

  int t = threadIdx.x;
  int l = t & 63;
  int wv = t >> 6;
  int wm = wv >> 1, wn = wv & 1;  // 2x2 wave grid, each wave 64x64

  int srow = l >> 3;   // staging: lane's row within an 8-row call group
  int sc8 = l & 7;     // lane's 16B chunk within a 128B row

  f32x4 zero = {0.f, 0.f, 0.f, 0.f};
  f32x4 acc[4][4];
#pragma unroll
  for (int mi = 0; mi < 4; mi++)
#pragma unroll
    for (int ni = 0; ni < 4; ni++) acc[mi][ni] = zero;

  for (int kt = 0; kt < 4; kt++) {
    if (kt) __syncthreads();   // all waves done reading previous tile
    int gk = kt * 64 + sc8 * 8;
#pragma unroll
    for (int j = 0; j < 4; j++) {
      int rb8 = (wv * 4 + j) * 8;  // this call's first row (wave-uniform)
      const unsigned short* ga = hbuf + (size_t)(m_base + rb8 + srow) * 256 + gk;
      __builtin_amdgcn_global_load_lds((gas_t)ga, (las_t)(ldsA + rb8 * 64), 16, 0, 0);
      const unsigned short* gb = w2T + (size_t)(n_base + rb8 + srow) * 256 + gk;
      __builtin_amdgcn_global_load_lds((gas_t)gb, (las_t)(ldsB + rb8 * 64), 16, 0, 0);
    }
    __syncthreads();  // implies vmcnt(0): staged data visible

#pragma unroll
    for (int ks = 0; ks < 2; ks++) {
      int c8 = ks * 4 + (l >> 4);
      s16x8 af[4], bfr[4];
#pragma unroll
      for (int mi = 0; mi < 4; mi++) {
        int row = wm * 64 + mi * 16 + (l & 15);
        af[mi] = *reinterpret_cast<const s16x8*>(ldsA + row * 64 + c8 * 8);
      }
#pragma unroll
      for (int ni = 0; ni < 4; ni++) {
        int row = wn * 64 + ni * 16 + (l & 15);
        bfr[ni] = *reinterpret_cast<const s16x8*>(ldsB + row * 64 + c8 * 8);
      }
#pragma unroll
      for (int mi = 0; mi < 4; mi++)
#pragma unroll
        for (int ni = 0; ni < 4; ni++)
          acc[mi][ni] = __builtin_amdgcn_mfma_f32_16x16x32_bf16(
              af[mi], bfr[ni], acc[mi][ni], 0, 0, 0);
    }
  }

  // epilogue: + b2, f32 store
#pragma unroll
  for (int ni = 0; ni < 4; ni++) {
    int col = n_base + wn * 64 + ni * 16 + (l & 15);
    float bias = b2[col];
#pragma unroll
    for (int mi = 0; mi < 4; mi++) {
      int row0 = m_base + wm * 64 + mi * 16 + ((l >> 4) * 4);
#pragma unroll
      for (int j = 0; j < 4; j++)
        out[(size_t)(row0 + j) * V + col] = acc[mi][ni][j] + bias;
    }
  }
}

// ---------------------------------------------------------------------------
extern "C" void kernel_launch(void* const* d_in, const int* in_sizes, int n_in,
                              void* d_out, int out_size, void* d_ws,
                              size_t ws_size, hipStream_t stream) {
  const int* tokens = (const int*)d_in[0];     // (S, B)
  const float* embed = (const float*)d_in[1];  // (V, E)
  const float* w1 = (const float*)d_in[2];     // (K1, H)
  const float* b1 = (const float*)d_in[3];     // (H)
  const float* w2 = (const float*)d_in[4];     // (H, V)
  const float* b2 = (const float*)d_in[5];     // (V)
  float* out = (float*)d_out;

  unsigned short* w2T = (unsigned short*)d_ws;          // V*E   bf16
  unsigned short* w1T = w2T + (size_t)V * E;            // H*K1  bf16
  unsigned short* hb  = w1T + (size_t)H * K1;           // M*H   bf16
  // total ~21 MB

  k_transpose_cast<<<dim3(V / 32, H / 32), 256, 0, stream>>>(w2, w2T, H, V);
  k_transpose_cast<<<dim3(H / 32, K1 / 32), 256, 0, stream>>>(w1, w1T, K1, H);
  k_stage1<<<512, 256, 0, stream>>>(tokens, embed, w1T, b1, hb);
  k_stage2<<<16000, 256, 0, stream>>>(hb, w2T, b2, out);
}